// Round 10
// baseline (315.048 us; speedup 1.0000x reference)
//
#include <hip/hip_runtime.h>
#include <hip/hip_bf16.h>

// Problem constants (match reference)
#define NN 50000
#define NE 800000
#define HID 128
#define NG 512
#define BN_EPS 1e-5f

typedef __attribute__((ext_vector_type(8))) short bf16x8;
typedef __attribute__((ext_vector_type(4))) float f32x4;

__device__ __forceinline__ ushort f2bf(float f) {
    uint u = __float_as_uint(f);
    uint r = (u + 0x7fffu + ((u >> 16) & 1u)) >> 16;
    return (ushort)r;
}
__device__ __forceinline__ float bf_lo(uint v) { return __uint_as_float(v << 16); }
__device__ __forceinline__ float bf_hi(uint v) { return __uint_as_float(v & 0xffff0000u); }

// ---------------------------------------------------------------------------
// Merged front-end: histogram (+rank capture, 4 edges/thread), fp32->bf16
// convert, weight pack, pooled zero. Hist first (feeds the serial scan chain);
// convert waves co-schedule into hist's atomic-latency bubbles.
// Hist is AT the device atomic-rmw ceiling (~18.5G/s = 8 XCD x 2.4GHz x 1/cyc).
// ---------------------------------------------------------------------------
#define HIST_BLOCKS 782   // ceil((NE/4)/256), 4 edges/thread
#define CONV_BLOCKS 6250  // NN*HID/4 float4 / 256 exact
#define WPREP_BLOCKS 32   // 128 wave-units / 4
#define POOLZ_BLOCKS 64   // NG*HID/4 float4 / 256 exact
#define PH_GRID (HIST_BLOCKS + CONV_BLOCKS + WPREP_BLOCKS + POOLZ_BLOCKS)

__global__ __launch_bounds__(256) void prep_hist_kernel(const int* __restrict__ ei,
                                                        int* __restrict__ deg,
                                                        int* __restrict__ rank,
                                                        const float* __restrict__ x,
                                                        ushort* __restrict__ xb,
                                                        const float* __restrict__ W0,
                                                        const float* __restrict__ W1,
                                                        const float* __restrict__ W2,
                                                        const float* __restrict__ W3,
                                                        ushort* __restrict__ Wp,
                                                        float* __restrict__ pooled) {
    uint b = blockIdx.x;
    if (b < HIST_BLOCKS) {
        int e4 = b * 256 + threadIdx.x;
        if (e4 < NE / 4) {
            int4 dst = ((const int4*)(ei + NE))[e4];
            int4 rk;
            rk.x = atomicAdd(&deg[dst.x], 1);
            rk.y = atomicAdd(&deg[dst.y], 1);
            rk.z = atomicAdd(&deg[dst.z], 1);
            rk.w = atomicAdd(&deg[dst.w], 1);
            ((int4*)rank)[e4] = rk;
        }
    } else if (b < HIST_BLOCKS + CONV_BLOCKS) {
        int i = (b - HIST_BLOCKS) * 256 + threadIdx.x;  // < 1,600,000 exactly
        float4 v = ((const float4*)x)[i];
        ushort4 o;
        o.x = f2bf(v.x);
        o.y = f2bf(v.y);
        o.z = f2bf(v.z);
        o.w = f2bf(v.w);
        ((ushort4*)xb)[i] = o;
    } else if (b < HIST_BLOCKS + CONV_BLOCKS + WPREP_BLOCKS) {
        int wu = (b - HIST_BLOCKS - CONV_BLOCKS) * 4 + (threadIdx.x >> 6);
        if (wu >= 128) return;
        int lane = threadIdx.x & 63;
        int m = wu >> 5;
        int g = wu & 31;
        int tile = g >> 2;
        int chunk = g & 3;
        const float* W = (m == 0) ? W0 : (m == 1) ? W1 : (m == 2) ? W2 : W3;
        int col = tile * 16 + (lane & 15);
        int k0 = chunk * 32 + (lane >> 4) * 8;
        ushort* dst = Wp + ((size_t)wu * 64 + lane) * 8;
#pragma unroll
        for (int j = 0; j < 8; ++j) dst[j] = f2bf(W[col * HID + k0 + j]);
    } else {
        int i = (b - HIST_BLOCKS - CONV_BLOCKS - WPREP_BLOCKS) * 256 + threadIdx.x;  // < 16384
        ((float4*)pooled)[i] = make_float4(0.f, 0.f, 0.f, 0.f);
    }
}

// ---------------------------------------------------------------------------
// Scan: per-block exclusive scan (wave shuffle based) -> cross-block fixup
// ---------------------------------------------------------------------------
__global__ __launch_bounds__(256) void scan1_kernel(const int* __restrict__ deg,
                                                    int* __restrict__ row_start,
                                                    int* __restrict__ bsums, int n) {
    __shared__ int wsum[4];
    int i = blockIdx.x * 256 + threadIdx.x;
    int lane = threadIdx.x & 63;
    int wid = threadIdx.x >> 6;
    int v = (i < n) ? deg[i] : 0;
    // wave-inclusive scan
    int sc = v;
#pragma unroll
    for (int off = 1; off < 64; off <<= 1) {
        int t = __shfl_up(sc, off);
        if (lane >= off) sc += t;
    }
    if (lane == 63) wsum[wid] = sc;
    __syncthreads();
    int wpre = 0;
#pragma unroll
    for (int k = 0; k < 4; ++k) wpre += (k < wid) ? wsum[k] : 0;
    if (i < n) row_start[i] = wpre + sc - v;  // block-exclusive
    if (threadIdx.x == 255) bsums[blockIdx.x] = wpre + sc;
}

// merged scan2+scan3: each block reduces bsums[0..blockIdx) and adds.
// scanBlocks = 196 < 256, so one 256-thread pass covers the whole prefix.
__global__ __launch_bounds__(256) void scan23_kernel(int* __restrict__ row_start,
                                                     const int* __restrict__ bsums, int n) {
    __shared__ int sred[4];
    int v = (threadIdx.x < blockIdx.x) ? bsums[threadIdx.x] : 0;
#pragma unroll
    for (int off = 32; off > 0; off >>= 1) v += __shfl_xor(v, off);
    if ((threadIdx.x & 63) == 0) sred[threadIdx.x >> 6] = v;
    __syncthreads();
    int total = sred[0] + sred[1] + sred[2] + sred[3];
    int i = blockIdx.x * 256 + threadIdx.x;
    if (i < n) row_start[i] += total;
}

// atomic-free fill, 4 edges/thread (int4 loads of src/dst/rank ->
// 4 independent row_start gathers + scatters in flight per lane)
__global__ __launch_bounds__(256) void fill_kernel(const int* __restrict__ ei,
                                                   const int* __restrict__ row_start,
                                                   const int* __restrict__ rank,
                                                   int* __restrict__ srclist) {
    int e4 = blockIdx.x * 256 + threadIdx.x;
    if (e4 >= NE / 4) return;
    int4 src = ((const int4*)ei)[e4];
    int4 dst = ((const int4*)(ei + NE))[e4];
    int4 rk = ((const int4*)rank)[e4];
    int p0 = row_start[dst.x] + rk.x;
    int p1 = row_start[dst.y] + rk.y;
    int p2 = row_start[dst.z] + rk.z;
    int p3 = row_start[dst.w] + rk.w;
    srclist[p0] = src.x;
    srclist[p1] = src.y;
    srclist[p2] = src.z;
    srclist[p3] = src.w;
}

// ---------------------------------------------------------------------------
// XCD-sliced mean aggregation (bf16).
// Row (256B) split into 4 x 64B slices; block b handles slice b&3. With the
// round-robin blockIdx->XCD mapping, XCD k only touches slice k%4 of the
// feature table = 3.2 MB -> fully L2-resident (4 MiB/XCD), turning the LLC
// gather into an L2-local one. srclist read nontemporally so the 3.2 MB index
// stream doesn't evict the resident slice.
// Wave = 16 independent node slots x 4 lanes x 16B (no cross-lane reduction,
// no DS traffic). 4 clamped/masked neighbors per round in flight per slot.
// fp32 accumulate, bf16 out (same rounding as before).
// ---------------------------------------------------------------------------
#define AGG_SLICES 4
__global__ __launch_bounds__(256) void aggregate_kernel(const ushort* __restrict__ feat,
                                                        const int* __restrict__ row_start,
                                                        const int* __restrict__ deg,
                                                        const int* __restrict__ srclist,
                                                        ushort* __restrict__ mean, int n) {
    int slice = blockIdx.x & (AGG_SLICES - 1);
    int nb = blockIdx.x >> 2;
    int wave = threadIdx.x >> 6;
    int lane = threadIdx.x & 63;
    int slot = lane >> 2;  // 16 node slots per wave
    int cl = lane & 3;     // uint4 within the 64B slice
    int node = (nb * 4 + wave) * 16 + slot;
    if (node >= n) return;
    int s0 = row_start[node];
    int d = deg[node];
    const uint4* fb = (const uint4*)feat;  // 16 uint4 per row
    int coff = slice * 4 + cl;

    float a[8];
#pragma unroll
    for (int i = 0; i < 8; ++i) a[i] = 0.f;

    int dm1 = d - 1;
    for (int j = 0; j < d; j += 4) {
        int i0 = __builtin_nontemporal_load(srclist + s0 + j);
        int i1 = __builtin_nontemporal_load(srclist + s0 + min(j + 1, dm1));
        int i2 = __builtin_nontemporal_load(srclist + s0 + min(j + 2, dm1));
        int i3 = __builtin_nontemporal_load(srclist + s0 + min(j + 3, dm1));
        uint4 v0 = fb[(size_t)i0 * 16 + coff];
        uint4 v1 = fb[(size_t)i1 * 16 + coff];
        uint4 v2 = fb[(size_t)i2 * 16 + coff];
        uint4 v3 = fb[(size_t)i3 * 16 + coff];
        float m1 = (j + 1 < d) ? 1.f : 0.f;
        float m2 = (j + 2 < d) ? 1.f : 0.f;
        float m3 = (j + 3 < d) ? 1.f : 0.f;
        a[0] += bf_lo(v0.x) + m1 * bf_lo(v1.x) + m2 * bf_lo(v2.x) + m3 * bf_lo(v3.x);
        a[1] += bf_hi(v0.x) + m1 * bf_hi(v1.x) + m2 * bf_hi(v2.x) + m3 * bf_hi(v3.x);
        a[2] += bf_lo(v0.y) + m1 * bf_lo(v1.y) + m2 * bf_lo(v2.y) + m3 * bf_lo(v3.y);
        a[3] += bf_hi(v0.y) + m1 * bf_hi(v1.y) + m2 * bf_hi(v2.y) + m3 * bf_hi(v3.y);
        a[4] += bf_lo(v0.z) + m1 * bf_lo(v1.z) + m2 * bf_lo(v2.z) + m3 * bf_lo(v3.z);
        a[5] += bf_hi(v0.z) + m1 * bf_hi(v1.z) + m2 * bf_hi(v2.z) + m3 * bf_hi(v3.z);
        a[6] += bf_lo(v0.w) + m1 * bf_lo(v1.w) + m2 * bf_lo(v2.w) + m3 * bf_lo(v3.w);
        a[7] += bf_hi(v0.w) + m1 * bf_hi(v1.w) + m2 * bf_hi(v2.w) + m3 * bf_hi(v3.w);
    }

    float inv = 1.0f / fmaxf((float)d, 1.0f);
    uint4 o;
    o.x = (uint)f2bf(a[0] * inv) | ((uint)f2bf(a[1] * inv) << 16);
    o.y = (uint)f2bf(a[2] * inv) | ((uint)f2bf(a[3] * inv) << 16);
    o.z = (uint)f2bf(a[4] * inv) | ((uint)f2bf(a[5] * inv) << 16);
    o.w = (uint)f2bf(a[6] * inv) | ((uint)f2bf(a[7] * inv) << 16);
    ((uint4*)mean)[(size_t)node * 16 + coff] = o;
}

// ---------------------------------------------------------------------------
// MFMA SAGE linear: out = mean @ Wl^T + root @ Wr^T + b.
// One wave per 16 rows x 128 cols; no LDS, no barriers.
// POOL variant fuses global_add_pool: rows grouped by (sorted) batch id,
// fp32 partial sums atomicAdd'ed straight into pooled[g][col].
// ---------------------------------------------------------------------------
template <bool POOL>
__global__ __launch_bounds__(256) void sage_gemm_mfma(const ushort* __restrict__ Amean,
                                                      const ushort* __restrict__ Aroot,
                                                      const ushort* __restrict__ WpL,
                                                      const float* __restrict__ bias,
                                                      const int* __restrict__ batch,
                                                      void* __restrict__ outv, int nwaves) {
    int w = blockIdx.x * 4 + (threadIdx.x >> 6);
    if (w >= nwaves) return;
    int lane = threadIdx.x & 63;
    int mrow = lane & 15;
    int quad = lane >> 4;
    int r0 = w * 16;

    f32x4 acc[8];
#pragma unroll
    for (int t = 0; t < 8; ++t) acc[t] = (f32x4){0.f, 0.f, 0.f, 0.f};

    const ushort* arow_m = Amean + ((size_t)(r0 + mrow)) * HID + quad * 8;
    const ushort* arow_r = Aroot + ((size_t)(r0 + mrow)) * HID + quad * 8;

#pragma unroll
    for (int half = 0; half < 2; ++half) {
        const ushort* arow = half ? arow_r : arow_m;
        const ushort* wb = WpL + (size_t)half * 16384 + (size_t)lane * 8;
#pragma unroll
        for (int c = 0; c < 4; ++c) {
            bf16x8 a = *(const bf16x8*)(arow + c * 32);
#pragma unroll
            for (int t = 0; t < 8; ++t) {
                bf16x8 b = *(const bf16x8*)(wb + (size_t)(t * 4 + c) * 512);
                acc[t] = __builtin_amdgcn_mfma_f32_16x16x32_bf16(a, b, acc[t], 0, 0, 0);
            }
        }
    }

    if (POOL) {
        float* pooled = (float*)outv;
        int rbase = r0 + quad * 4;
        int g0 = batch[rbase + 0];
        int g1 = batch[rbase + 1];
        int g2 = batch[rbase + 2];
        int g3 = batch[rbase + 3];
#pragma unroll
        for (int t = 0; t < 8; ++t) {
            int col = t * 16 + mrow;
            float bv = bias[col];
            float v0 = acc[t][0] + bv;
            float v1 = acc[t][1] + bv;
            float v2 = acc[t][2] + bv;
            float v3 = acc[t][3] + bv;
            int cg = g0;
            float s = v0;
            if (g1 == cg) s += v1; else { atomicAdd(&pooled[(size_t)cg * HID + col], s); cg = g1; s = v1; }
            if (g2 == cg) s += v2; else { atomicAdd(&pooled[(size_t)cg * HID + col], s); cg = g2; s = v2; }
            if (g3 == cg) s += v3; else { atomicAdd(&pooled[(size_t)cg * HID + col], s); cg = g3; s = v3; }
            atomicAdd(&pooled[(size_t)cg * HID + col], s);
        }
    } else {
        ushort* out = (ushort*)outv;
#pragma unroll
        for (int t = 0; t < 8; ++t) {
            int col = t * 16 + mrow;
            float bv = bias[col];
#pragma unroll
            for (int r = 0; r < 4; ++r) {
                int row = r0 + quad * 4 + r;
                out[(size_t)row * HID + col] = f2bf(acc[t][r] + bv);
            }
        }
    }
}

// ---------------------------------------------------------------------------
// Tail: lin1 + BN(eval) + relu + lin2. One block (128 thr) per graph.
// ---------------------------------------------------------------------------
__global__ __launch_bounds__(128) void tail_kernel(const float* __restrict__ pooled,
                                                   const float* __restrict__ lin1_w,
                                                   const float* __restrict__ lin1_b,
                                                   const float* __restrict__ lin2_w,
                                                   const float* __restrict__ lin2_b,
                                                   const float* __restrict__ gamma,
                                                   const float* __restrict__ beta,
                                                   const float* __restrict__ rmean,
                                                   const float* __restrict__ rvar,
                                                   float* __restrict__ out) {
    __shared__ float Wt[64 * 128];  // Wt[k][c ^ (k&31)] = lin1_w[c][k0+k]
    __shared__ float p[128];
    __shared__ float tbuf[128];
    int g = blockIdx.x;
    int c = threadIdx.x;
    p[c] = pooled[g * HID + c];
    float acc = lin1_b[c];
    int kk = c & 63;
    int chalf = c >> 6;
    for (int k0 = 0; k0 < 128; k0 += 64) {
        __syncthreads();
        for (int i = 0; i < 64; ++i) {
            int crow = i * 2 + chalf;
            float v = lin1_w[crow * HID + k0 + kk];
            Wt[kk * 128 + (crow ^ (kk & 31))] = v;
        }
        __syncthreads();
#pragma unroll
        for (int k = 0; k < 64; ++k) {
            acc += p[k0 + k] * Wt[k * 128 + (c ^ (k & 31))];
        }
    }
    float v = (acc - rmean[c]) * rsqrtf(rvar[c] + BN_EPS) * gamma[c] + beta[c];
    v = fmaxf(v, 0.f);
    tbuf[c] = v;
    __syncthreads();
    int j = c >> 6;
    int lane = c & 63;
    float partial = tbuf[lane] * lin2_w[j * HID + lane] +
                    tbuf[lane + 64] * lin2_w[j * HID + lane + 64];
    for (int off = 32; off > 0; off >>= 1) partial += __shfl_down(partial, off);
    if (lane == 0) out[g * 2 + j] = partial + lin2_b[j];
}

// ---------------------------------------------------------------------------
extern "C" void kernel_launch(void* const* d_in, const int* in_sizes, int n_in,
                              void* d_out, int out_size, void* d_ws, size_t ws_size,
                              hipStream_t stream) {
    const float* x = (const float*)d_in[0];
    const int* ei = (const int*)d_in[1];      // [2][E]
    const int* batch = (const int*)d_in[2];   // [N]
    const float* W1l = (const float*)d_in[3];
    const float* b1 = (const float*)d_in[4];
    const float* W1r = (const float*)d_in[5];
    const float* W2l = (const float*)d_in[6];
    const float* b2 = (const float*)d_in[7];
    const float* W2r = (const float*)d_in[8];
    const float* lin1_w = (const float*)d_in[9];
    const float* lin1_b = (const float*)d_in[10];
    const float* lin2_w = (const float*)d_in[11];
    const float* lin2_b = (const float*)d_in[12];
    const float* gamma = (const float*)d_in[13];
    const float* beta = (const float*)d_in[14];
    const float* rmean = (const float*)d_in[15];
    const float* rvar = (const float*)d_in[16];
    float* out = (float*)d_out;

    const int N = NN, E = NE;
    const int NWAVES = N / 16;  // 3125 exact

    // workspace carve (256B aligned)
    char* p = (char*)d_ws;
    auto carve = [&](size_t bytes) {
        void* r = (void*)p;
        p += (bytes + 255) & ~(size_t)255;
        return r;
    };
    int* deg = (int*)carve((size_t)N * 4);
    int* row_start = (int*)carve((size_t)N * 4);
    int* bsums = (int*)carve(1024 * 4);
    int* rank = (int*)carve((size_t)E * 4);
    int* srclist = (int*)carve((size_t)E * 4 + 64);
    ushort* xb = (ushort*)carve((size_t)N * HID * 2);
    ushort* meanb = (ushort*)carve((size_t)N * HID * 2);
    ushort* h1 = (ushort*)carve((size_t)N * HID * 2);
    float* pooled = (float*)carve((size_t)NG * HID * 4);
    ushort* Wp = (ushort*)carve(4 * 32 * 64 * 8 * 2);  // 128 KB

    // deg must be zero before hist atomics (pooled zeroed inside prep_hist)
    hipMemsetAsync(deg, 0, (size_t)N * 4, stream);

    // merged front-end: hist + convert + weight pack + pooled zero
    prep_hist_kernel<<<PH_GRID, 256, 0, stream>>>(ei, deg, rank, x, xb,
                                                  W1l, W1r, W2l, W2r, Wp, pooled);

    const int scanBlocks = (N + 255) / 256;  // 196
    scan1_kernel<<<scanBlocks, 256, 0, stream>>>(deg, row_start, bsums, N);
    scan23_kernel<<<scanBlocks, 256, 0, stream>>>(row_start, bsums, N);
    fill_kernel<<<(E / 4 + 255) / 256, 256, 0, stream>>>(ei, row_start, rank, srclist);

    const int aggBlocks = AGG_SLICES * ((N + 63) / 64);  // 4 slices x 782
    // layer 1 (bf16 h1 out)
    aggregate_kernel<<<aggBlocks, 256, 0, stream>>>(xb, row_start, deg, srclist, meanb, N);
    sage_gemm_mfma<false><<<(NWAVES + 3) / 4, 256, 0, stream>>>(meanb, xb, Wp, b1, nullptr, h1,
                                                                NWAVES);
    // layer 2 (fused global_add_pool)
    aggregate_kernel<<<aggBlocks, 256, 0, stream>>>(h1, row_start, deg, srclist, meanb, N);
    sage_gemm_mfma<true><<<(NWAVES + 3) / 4, 256, 0, stream>>>(meanb, h1, Wp + 32768, b2, batch,
                                                               pooled, NWAVES);
    // tail
    tail_kernel<<<NG, 128, 0, stream>>>(pooled, lin1_w, lin1_b, lin2_w, lin2_b,
                                        gamma, beta, rmean, rvar, out);
}

// Round 11
// 312.875 us; speedup vs baseline: 1.0069x; 1.0069x over previous
//
#include <hip/hip_runtime.h>
#include <hip/hip_bf16.h>

// Problem constants (match reference)
#define NN 50000
#define NE 800000
#define HID 128
#define NG 512
#define BN_EPS 1e-5f

typedef __attribute__((ext_vector_type(8))) short bf16x8;
typedef __attribute__((ext_vector_type(4))) float f32x4;

__device__ __forceinline__ ushort f2bf(float f) {
    uint u = __float_as_uint(f);
    uint r = (u + 0x7fffu + ((u >> 16) & 1u)) >> 16;
    return (ushort)r;
}
__device__ __forceinline__ float bf_lo(uint v) { return __uint_as_float(v << 16); }
__device__ __forceinline__ float bf_hi(uint v) { return __uint_as_float(v & 0xffff0000u); }

// load 8 consecutive fp32 and round to a bf16x8 MFMA fragment
__device__ __forceinline__ bf16x8 ld_frag_f32(const float* __restrict__ p) {
    float4 f0 = *(const float4*)p;
    float4 f1 = *(const float4*)(p + 4);
    bf16x8 r;
    r[0] = (short)f2bf(f0.x); r[1] = (short)f2bf(f0.y);
    r[2] = (short)f2bf(f0.z); r[3] = (short)f2bf(f0.w);
    r[4] = (short)f2bf(f1.x); r[5] = (short)f2bf(f1.y);
    r[6] = (short)f2bf(f1.z); r[7] = (short)f2bf(f1.w);
    return r;
}

// ---------------------------------------------------------------------------
// Merged front-end. Linearity trick: mean_agg(x)@W1l == mean_agg(x@W1l), so
// layer-1's dual GEMM (y1 = x@W1l, r1 = x@W1r + b1) needs NO CSR and runs
// here, co-scheduled into the histogram's atomic-latency bubbles (hist is AT
// the device atomic-rmw ceiling ~18.5G/s = 8 XCD x 2.4GHz x 1/cyc; its
// VALUBusy is ~1.4% -> plenty of idle VALU/MFMA issue slots).
// Block map: [0,782) hist | [782,1564) gemm1 | +16 wprep(W2) | +64 poolzero
// ---------------------------------------------------------------------------
#define HIST_BLOCKS 782   // ceil((NE/4)/256), 4 edges/thread
#define GEMM1_BLOCKS 782  // ceil(3125 waves / 4)
#define WPREP_BLOCKS 16   // 64 wave-units (2 matrices x 32 groups) / 4
#define POOLZ_BLOCKS 64   // NG*HID/4 float4 / 256 exact
#define PH_GRID (HIST_BLOCKS + GEMM1_BLOCKS + WPREP_BLOCKS + POOLZ_BLOCKS)

__global__ __launch_bounds__(256) void prep_hist_kernel(const int* __restrict__ ei,
                                                        int* __restrict__ deg,
                                                        int* __restrict__ rank,
                                                        const float* __restrict__ x,
                                                        const float* __restrict__ W1l,
                                                        const float* __restrict__ W1r,
                                                        const float* __restrict__ b1,
                                                        ushort* __restrict__ y1,
                                                        ushort* __restrict__ r1,
                                                        const float* __restrict__ W2l,
                                                        const float* __restrict__ W2r,
                                                        ushort* __restrict__ Wp,
                                                        float* __restrict__ pooled) {
    uint b = blockIdx.x;
    if (b < HIST_BLOCKS) {
        int e4 = b * 256 + threadIdx.x;
        if (e4 < NE / 4) {
            int4 dst = ((const int4*)(ei + NE))[e4];
            int4 rk;
            rk.x = atomicAdd(&deg[dst.x], 1);
            rk.y = atomicAdd(&deg[dst.y], 1);
            rk.z = atomicAdd(&deg[dst.z], 1);
            rk.w = atomicAdd(&deg[dst.w], 1);
            ((int4*)rank)[e4] = rk;
        }
    } else if (b < HIST_BLOCKS + GEMM1_BLOCKS) {
        // layer-1 dual GEMM: y1 = bf16(x)@bf16(W1l), r1 = bf16(x)@bf16(W1r)+b1
        int w = (b - HIST_BLOCKS) * 4 + (threadIdx.x >> 6);
        if (w >= NN / 16) return;  // 3125 waves
        int lane = threadIdx.x & 63;
        int mrow = lane & 15;
        int quad = lane >> 4;
        int r0 = w * 16;

        f32x4 accY[8], accR[8];
#pragma unroll
        for (int t = 0; t < 8; ++t) {
            accY[t] = (f32x4){0.f, 0.f, 0.f, 0.f};
            accR[t] = (f32x4){0.f, 0.f, 0.f, 0.f};
        }
        const float* xrow = x + (size_t)(r0 + mrow) * HID + quad * 8;
#pragma unroll
        for (int c = 0; c < 4; ++c) {
            bf16x8 a = ld_frag_f32(xrow + c * 32);
#pragma unroll
            for (int t = 0; t < 8; ++t) {
                // B-fragment built directly from fp32 W (L2-hot: shared by all waves)
                const float* wbase = (size_t)(t * 16 + mrow) * HID + c * 32 + quad * 8 + (float*)0;
                bf16x8 bl = ld_frag_f32(W1l + (size_t)(t * 16 + mrow) * HID + c * 32 + quad * 8);
                accY[t] = __builtin_amdgcn_mfma_f32_16x16x32_bf16(a, bl, accY[t], 0, 0, 0);
                bf16x8 br = ld_frag_f32(W1r + (size_t)(t * 16 + mrow) * HID + c * 32 + quad * 8);
                accR[t] = __builtin_amdgcn_mfma_f32_16x16x32_bf16(a, br, accR[t], 0, 0, 0);
                (void)wbase;
            }
        }
#pragma unroll
        for (int t = 0; t < 8; ++t) {
            int col = t * 16 + mrow;
            float bv = b1[col];
#pragma unroll
            for (int r = 0; r < 4; ++r) {
                int row = r0 + quad * 4 + r;
                y1[(size_t)row * HID + col] = f2bf(accY[t][r]);
                r1[(size_t)row * HID + col] = f2bf(accR[t][r] + bv);
            }
        }
    } else if (b < HIST_BLOCKS + GEMM1_BLOCKS + WPREP_BLOCKS) {
        // pack W2l/W2r into MFMA B-fragment order for gemm2pool
        int wu = (b - HIST_BLOCKS - GEMM1_BLOCKS) * 4 + (threadIdx.x >> 6);
        if (wu >= 64) return;
        int lane = threadIdx.x & 63;
        int m = wu >> 5;  // 0 = W2l, 1 = W2r
        int g = wu & 31;
        int tile = g >> 2;
        int chunk = g & 3;
        const float* W = (m == 0) ? W2l : W2r;
        int col = tile * 16 + (lane & 15);
        int k0 = chunk * 32 + (lane >> 4) * 8;
        ushort* dst = Wp + ((size_t)wu * 64 + lane) * 8;
#pragma unroll
        for (int j = 0; j < 8; ++j) dst[j] = f2bf(W[col * HID + k0 + j]);
    } else {
        int i = (b - HIST_BLOCKS - GEMM1_BLOCKS - WPREP_BLOCKS) * 256 + threadIdx.x;  // < 16384
        ((float4*)pooled)[i] = make_float4(0.f, 0.f, 0.f, 0.f);
    }
}

// ---------------------------------------------------------------------------
// Scan: per-block exclusive scan (wave shuffle based) -> cross-block fixup
// ---------------------------------------------------------------------------
__global__ __launch_bounds__(256) void scan1_kernel(const int* __restrict__ deg,
                                                    int* __restrict__ row_start,
                                                    int* __restrict__ bsums, int n) {
    __shared__ int wsum[4];
    int i = blockIdx.x * 256 + threadIdx.x;
    int lane = threadIdx.x & 63;
    int wid = threadIdx.x >> 6;
    int v = (i < n) ? deg[i] : 0;
    int sc = v;
#pragma unroll
    for (int off = 1; off < 64; off <<= 1) {
        int t = __shfl_up(sc, off);
        if (lane >= off) sc += t;
    }
    if (lane == 63) wsum[wid] = sc;
    __syncthreads();
    int wpre = 0;
#pragma unroll
    for (int k = 0; k < 4; ++k) wpre += (k < wid) ? wsum[k] : 0;
    if (i < n) row_start[i] = wpre + sc - v;  // block-exclusive
    if (threadIdx.x == 255) bsums[blockIdx.x] = wpre + sc;
}

// merged scan2+scan3: each block reduces bsums[0..blockIdx) and adds.
__global__ __launch_bounds__(256) void scan23_kernel(int* __restrict__ row_start,
                                                     const int* __restrict__ bsums, int n) {
    __shared__ int sred[4];
    int v = (threadIdx.x < blockIdx.x) ? bsums[threadIdx.x] : 0;
#pragma unroll
    for (int off = 32; off > 0; off >>= 1) v += __shfl_xor(v, off);
    if ((threadIdx.x & 63) == 0) sred[threadIdx.x >> 6] = v;
    __syncthreads();
    int total = sred[0] + sred[1] + sred[2] + sred[3];
    int i = blockIdx.x * 256 + threadIdx.x;
    if (i < n) row_start[i] += total;
}

// atomic-free fill, 4 edges/thread
__global__ __launch_bounds__(256) void fill_kernel(const int* __restrict__ ei,
                                                   const int* __restrict__ row_start,
                                                   const int* __restrict__ rank,
                                                   int* __restrict__ srclist) {
    int e4 = blockIdx.x * 256 + threadIdx.x;
    if (e4 >= NE / 4) return;
    int4 src = ((const int4*)ei)[e4];
    int4 dst = ((const int4*)(ei + NE))[e4];
    int4 rk = ((const int4*)rank)[e4];
    int p0 = row_start[dst.x] + rk.x;
    int p1 = row_start[dst.y] + rk.y;
    int p2 = row_start[dst.z] + rk.z;
    int p3 = row_start[dst.w] + rk.w;
    srclist[p0] = src.x;
    srclist[p1] = src.y;
    srclist[p2] = src.z;
    srclist[p3] = src.w;
}

// ---------------------------------------------------------------------------
// Mean aggregation (bf16): one wave per node (R9 proven-best structure).
// Lane layout: cl = lane&15 -> 16B column chunk, sub = lane>>4 -> 4 neighbor
// slots. Main loop 16 neighbors/iter; tail = one masked full-depth round
// (clamped indices, fma-masked). ADD_R fuses "+ r[node]" (layer-1 root path).
// fp32 accumulate, bf16 out.
// ---------------------------------------------------------------------------
template <bool ADD_R>
__global__ __launch_bounds__(256) void aggregate_kernel(const ushort* __restrict__ feat,
                                                        const int* __restrict__ row_start,
                                                        const int* __restrict__ deg,
                                                        const int* __restrict__ srclist,
                                                        const ushort* __restrict__ rres,
                                                        ushort* __restrict__ outbuf, int n) {
    int node = blockIdx.x * 4 + (threadIdx.x >> 6);
    if (node >= n) return;
    int lane = threadIdx.x & 63;
    int cl = lane & 15;
    int sub = lane >> 4;
    const uint4* fb = (const uint4*)feat;  // row stride = 16 uint4
    int s0 = row_start[node];
    int d = deg[node];

    float a[8];
#pragma unroll
    for (int i = 0; i < 8; ++i) a[i] = 0.f;

    int j = 0;
    for (; j + 16 <= d; j += 16) {
        int i0 = srclist[s0 + j + sub];
        int i1 = srclist[s0 + j + 4 + sub];
        int i2 = srclist[s0 + j + 8 + sub];
        int i3 = srclist[s0 + j + 12 + sub];
        uint4 v0 = fb[(size_t)i0 * 16 + cl];
        uint4 v1 = fb[(size_t)i1 * 16 + cl];
        uint4 v2 = fb[(size_t)i2 * 16 + cl];
        uint4 v3 = fb[(size_t)i3 * 16 + cl];
        a[0] += (bf_lo(v0.x) + bf_lo(v1.x)) + (bf_lo(v2.x) + bf_lo(v3.x));
        a[1] += (bf_hi(v0.x) + bf_hi(v1.x)) + (bf_hi(v2.x) + bf_hi(v3.x));
        a[2] += (bf_lo(v0.y) + bf_lo(v1.y)) + (bf_lo(v2.y) + bf_lo(v3.y));
        a[3] += (bf_hi(v0.y) + bf_hi(v1.y)) + (bf_hi(v2.y) + bf_hi(v3.y));
        a[4] += (bf_lo(v0.z) + bf_lo(v1.z)) + (bf_lo(v2.z) + bf_lo(v3.z));
        a[5] += (bf_hi(v0.z) + bf_hi(v1.z)) + (bf_hi(v2.z) + bf_hi(v3.z));
        a[6] += (bf_lo(v0.w) + bf_lo(v1.w)) + (bf_lo(v2.w) + bf_lo(v3.w));
        a[7] += (bf_hi(v0.w) + bf_hi(v1.w)) + (bf_hi(v2.w) + bf_hi(v3.w));
    }
    if (j < d) {
        int dm1 = d - 1;
        int k0 = j + sub;
        int k1 = j + 4 + sub;
        int k2 = j + 8 + sub;
        int k3 = j + 12 + sub;
        int i0 = srclist[s0 + min(k0, dm1)];
        int i1 = srclist[s0 + min(k1, dm1)];
        int i2 = srclist[s0 + min(k2, dm1)];
        int i3 = srclist[s0 + min(k3, dm1)];
        uint4 v0 = fb[(size_t)i0 * 16 + cl];
        uint4 v1 = fb[(size_t)i1 * 16 + cl];
        uint4 v2 = fb[(size_t)i2 * 16 + cl];
        uint4 v3 = fb[(size_t)i3 * 16 + cl];
        float m0 = (k0 < d) ? 1.f : 0.f;
        float m1 = (k1 < d) ? 1.f : 0.f;
        float m2 = (k2 < d) ? 1.f : 0.f;
        float m3 = (k3 < d) ? 1.f : 0.f;
        a[0] += m0 * bf_lo(v0.x) + m1 * bf_lo(v1.x) + m2 * bf_lo(v2.x) + m3 * bf_lo(v3.x);
        a[1] += m0 * bf_hi(v0.x) + m1 * bf_hi(v1.x) + m2 * bf_hi(v2.x) + m3 * bf_hi(v3.x);
        a[2] += m0 * bf_lo(v0.y) + m1 * bf_lo(v1.y) + m2 * bf_lo(v2.y) + m3 * bf_lo(v3.y);
        a[3] += m0 * bf_hi(v0.y) + m1 * bf_hi(v1.y) + m2 * bf_hi(v2.y) + m3 * bf_hi(v3.y);
        a[4] += m0 * bf_lo(v0.z) + m1 * bf_lo(v1.z) + m2 * bf_lo(v2.z) + m3 * bf_lo(v3.z);
        a[5] += m0 * bf_hi(v0.z) + m1 * bf_hi(v1.z) + m2 * bf_hi(v2.z) + m3 * bf_hi(v3.z);
        a[6] += m0 * bf_lo(v0.w) + m1 * bf_lo(v1.w) + m2 * bf_lo(v2.w) + m3 * bf_lo(v3.w);
        a[7] += m0 * bf_hi(v0.w) + m1 * bf_hi(v1.w) + m2 * bf_hi(v2.w) + m3 * bf_hi(v3.w);
    }

#pragma unroll
    for (int i = 0; i < 8; ++i) {
        float v = a[i];
        v += __shfl_xor(v, 16);
        v += __shfl_xor(v, 32);
        a[i] = v;
    }

    if (sub == 0) {
        float inv = 1.0f / fmaxf((float)d, 1.0f);
        float h[8];
#pragma unroll
        for (int i = 0; i < 8; ++i) h[i] = a[i] * inv;
        if (ADD_R) {
            uint4 rv = ((const uint4*)rres)[(size_t)node * 16 + cl];
            h[0] += bf_lo(rv.x); h[1] += bf_hi(rv.x);
            h[2] += bf_lo(rv.y); h[3] += bf_hi(rv.y);
            h[4] += bf_lo(rv.z); h[5] += bf_hi(rv.z);
            h[6] += bf_lo(rv.w); h[7] += bf_hi(rv.w);
        }
        uint4 o;
        o.x = (uint)f2bf(h[0]) | ((uint)f2bf(h[1]) << 16);
        o.y = (uint)f2bf(h[2]) | ((uint)f2bf(h[3]) << 16);
        o.z = (uint)f2bf(h[4]) | ((uint)f2bf(h[5]) << 16);
        o.w = (uint)f2bf(h[6]) | ((uint)f2bf(h[7]) << 16);
        ((uint4*)outbuf)[(size_t)node * 16 + cl] = o;
    }
}

// ---------------------------------------------------------------------------
// MFMA SAGE linear (layer 2): out = mean @ W2l^T + root @ W2r^T + b, fused
// global_add_pool epilogue (rows grouped by sorted batch id, fp32 atomics).
// One wave per 16 rows x 128 cols; no LDS, no barriers.
// ---------------------------------------------------------------------------
__global__ __launch_bounds__(256) void sage_gemm_pool(const ushort* __restrict__ Amean,
                                                      const ushort* __restrict__ Aroot,
                                                      const ushort* __restrict__ WpL,
                                                      const float* __restrict__ bias,
                                                      const int* __restrict__ batch,
                                                      float* __restrict__ pooled, int nwaves) {
    int w = blockIdx.x * 4 + (threadIdx.x >> 6);
    if (w >= nwaves) return;
    int lane = threadIdx.x & 63;
    int mrow = lane & 15;
    int quad = lane >> 4;
    int r0 = w * 16;

    f32x4 acc[8];
#pragma unroll
    for (int t = 0; t < 8; ++t) acc[t] = (f32x4){0.f, 0.f, 0.f, 0.f};

    const ushort* arow_m = Amean + ((size_t)(r0 + mrow)) * HID + quad * 8;
    const ushort* arow_r = Aroot + ((size_t)(r0 + mrow)) * HID + quad * 8;

#pragma unroll
    for (int half = 0; half < 2; ++half) {
        const ushort* arow = half ? arow_r : arow_m;
        const ushort* wb = WpL + (size_t)half * 16384 + (size_t)lane * 8;
#pragma unroll
        for (int c = 0; c < 4; ++c) {
            bf16x8 a = *(const bf16x8*)(arow + c * 32);
#pragma unroll
            for (int t = 0; t < 8; ++t) {
                bf16x8 b = *(const bf16x8*)(wb + (size_t)(t * 4 + c) * 512);
                acc[t] = __builtin_amdgcn_mfma_f32_16x16x32_bf16(a, b, acc[t], 0, 0, 0);
            }
        }
    }

    int rbase = r0 + quad * 4;
    int g0 = batch[rbase + 0];
    int g1 = batch[rbase + 1];
    int g2 = batch[rbase + 2];
    int g3 = batch[rbase + 3];
#pragma unroll
    for (int t = 0; t < 8; ++t) {
        int col = t * 16 + mrow;
        float bv = bias[col];
        float v0 = acc[t][0] + bv;
        float v1 = acc[t][1] + bv;
        float v2 = acc[t][2] + bv;
        float v3 = acc[t][3] + bv;
        int cg = g0;
        float s = v0;
        if (g1 == cg) s += v1; else { atomicAdd(&pooled[(size_t)cg * HID + col], s); cg = g1; s = v1; }
        if (g2 == cg) s += v2; else { atomicAdd(&pooled[(size_t)cg * HID + col], s); cg = g2; s = v2; }
        if (g3 == cg) s += v3; else { atomicAdd(&pooled[(size_t)cg * HID + col], s); cg = g3; s = v3; }
        atomicAdd(&pooled[(size_t)cg * HID + col], s);
    }
}

// ---------------------------------------------------------------------------
// Tail: lin1 + BN(eval) + relu + lin2. One block (128 thr) per graph.
// ---------------------------------------------------------------------------
__global__ __launch_bounds__(128) void tail_kernel(const float* __restrict__ pooled,
                                                   const float* __restrict__ lin1_w,
                                                   const float* __restrict__ lin1_b,
                                                   const float* __restrict__ lin2_w,
                                                   const float* __restrict__ lin2_b,
                                                   const float* __restrict__ gamma,
                                                   const float* __restrict__ beta,
                                                   const float* __restrict__ rmean,
                                                   const float* __restrict__ rvar,
                                                   float* __restrict__ out) {
    __shared__ float Wt[64 * 128];  // Wt[k][c ^ (k&31)] = lin1_w[c][k0+k]
    __shared__ float p[128];
    __shared__ float tbuf[128];
    int g = blockIdx.x;
    int c = threadIdx.x;
    p[c] = pooled[g * HID + c];
    float acc = lin1_b[c];
    int kk = c & 63;
    int chalf = c >> 6;
    for (int k0 = 0; k0 < 128; k0 += 64) {
        __syncthreads();
        for (int i = 0; i < 64; ++i) {
            int crow = i * 2 + chalf;
            float v = lin1_w[crow * HID + k0 + kk];
            Wt[kk * 128 + (crow ^ (kk & 31))] = v;
        }
        __syncthreads();
#pragma unroll
        for (int k = 0; k < 64; ++k) {
            acc += p[k0 + k] * Wt[k * 128 + (c ^ (k & 31))];
        }
    }
    float v = (acc - rmean[c]) * rsqrtf(rvar[c] + BN_EPS) * gamma[c] + beta[c];
    v = fmaxf(v, 0.f);
    tbuf[c] = v;
    __syncthreads();
    int j = c >> 6;
    int lane = c & 63;
    float partial = tbuf[lane] * lin2_w[j * HID + lane] +
                    tbuf[lane + 64] * lin2_w[j * HID + lane + 64];
    for (int off = 32; off > 0; off >>= 1) partial += __shfl_down(partial, off);
    if (lane == 0) out[g * 2 + j] = partial + lin2_b[j];
}

// ---------------------------------------------------------------------------
extern "C" void kernel_launch(void* const* d_in, const int* in_sizes, int n_in,
                              void* d_out, int out_size, void* d_ws, size_t ws_size,
                              hipStream_t stream) {
    const float* x = (const float*)d_in[0];
    const int* ei = (const int*)d_in[1];      // [2][E]
    const int* batch = (const int*)d_in[2];   // [N]
    const float* W1l = (const float*)d_in[3];
    const float* b1 = (const float*)d_in[4];
    const float* W1r = (const float*)d_in[5];
    const float* W2l = (const float*)d_in[6];
    const float* b2 = (const float*)d_in[7];
    const float* W2r = (const float*)d_in[8];
    const float* lin1_w = (const float*)d_in[9];
    const float* lin1_b = (const float*)d_in[10];
    const float* lin2_w = (const float*)d_in[11];
    const float* lin2_b = (const float*)d_in[12];
    const float* gamma = (const float*)d_in[13];
    const float* beta = (const float*)d_in[14];
    const float* rmean = (const float*)d_in[15];
    const float* rvar = (const float*)d_in[16];
    float* out = (float*)d_out;

    const int N = NN, E = NE;
    const int NWAVES = N / 16;  // 3125 exact

    // workspace carve (256B aligned)
    char* p = (char*)d_ws;
    auto carve = [&](size_t bytes) {
        void* r = (void*)p;
        p += (bytes + 255) & ~(size_t)255;
        return r;
    };
    int* deg = (int*)carve((size_t)N * 4);
    int* row_start = (int*)carve((size_t)N * 4);
    int* bsums = (int*)carve(1024 * 4);
    int* rank = (int*)carve((size_t)E * 4);
    int* srclist = (int*)carve((size_t)E * 4 + 64);
    ushort* y1 = (ushort*)carve((size_t)N * HID * 2);
    ushort* r1 = (ushort*)carve((size_t)N * HID * 2);
    ushort* h1 = (ushort*)carve((size_t)N * HID * 2);
    ushort* meanb = (ushort*)carve((size_t)N * HID * 2);
    float* pooled = (float*)carve((size_t)NG * HID * 4);
    ushort* Wp = (ushort*)carve(2 * 32 * 64 * 8 * 2);  // 64 KB (W2l|W2r)

    // deg must be zero before hist atomics (pooled zeroed inside prep_hist)
    hipMemsetAsync(deg, 0, (size_t)N * 4, stream);

    // merged front-end: hist + layer-1 dual GEMM + W2 pack + pooled zero
    prep_hist_kernel<<<PH_GRID, 256, 0, stream>>>(ei, deg, rank, x, W1l, W1r, b1, y1, r1,
                                                  W2l, W2r, Wp, pooled);

    const int scanBlocks = (N + 255) / 256;  // 196
    scan1_kernel<<<scanBlocks, 256, 0, stream>>>(deg, row_start, bsums, N);
    scan23_kernel<<<scanBlocks, 256, 0, stream>>>(row_start, bsums, N);
    fill_kernel<<<(E / 4 + 255) / 256, 256, 0, stream>>>(ei, row_start, rank, srclist);

    // layer 1: h1 = gather-mean(y1) + r1   (linearity: mean_agg(x)@W == mean_agg(x@W))
    aggregate_kernel<true><<<(N + 3) / 4, 256, 0, stream>>>(y1, row_start, deg, srclist, r1,
                                                            h1, N);
    // layer 2: meanb = gather-mean(h1); then dual GEMM + fused pool
    aggregate_kernel<false><<<(N + 3) / 4, 256, 0, stream>>>(h1, row_start, deg, srclist,
                                                             nullptr, meanb, N);
    sage_gemm_pool<<<(NWAVES + 3) / 4, 256, 0, stream>>>(meanb, h1, Wp, b2, batch, pooled,
                                                         NWAVES);
    // tail
    tail_kernel<<<NG, 128, 0, stream>>>(pooled, lin1_w, lin1_b, lin2_w, lin2_b,
                                        gamma, beta, rmean, rvar, out);
}

// Round 12
// 260.135 us; speedup vs baseline: 1.2111x; 1.2027x over previous
//
#include <hip/hip_runtime.h>
#include <hip/hip_bf16.h>

// Problem constants (match reference)
#define NN 50000
#define NE 800000
#define HID 128
#define NG 512
#define BN_EPS 1e-5f

typedef __attribute__((ext_vector_type(8))) short bf16x8;
typedef __attribute__((ext_vector_type(4))) float f32x4;

__device__ __forceinline__ ushort f2bf(float f) {
    uint u = __float_as_uint(f);
    uint r = (u + 0x7fffu + ((u >> 16) & 1u)) >> 16;
    return (ushort)r;
}
__device__ __forceinline__ float bf_lo(uint v) { return __uint_as_float(v << 16); }
__device__ __forceinline__ float bf_hi(uint v) { return __uint_as_float(v & 0xffff0000u); }

// ---------------------------------------------------------------------------
// Merged front-end: histogram (+rank capture, 4 edges/thread), fp32->bf16
// convert, weight pack, pooled zero. All branches LOW-VGPR (12) so hist keeps
// ~60% occupancy -- R11 showed merging a high-VGPR GEMM here drops occupancy
// to 24% and triples hist time. Hist is AT the device atomic-rmw ceiling
// (~18.5G/s = 8 XCD x 2.4GHz x 1/cyc).
// ---------------------------------------------------------------------------
#define HIST_BLOCKS 782   // ceil((NE/4)/256), 4 edges/thread
#define CONV_BLOCKS 6250  // NN*HID/4 float4 / 256 exact
#define WPREP_BLOCKS 32   // 128 wave-units / 4
#define POOLZ_BLOCKS 64   // NG*HID/4 float4 / 256 exact
#define PH_GRID (HIST_BLOCKS + CONV_BLOCKS + WPREP_BLOCKS + POOLZ_BLOCKS)

__global__ __launch_bounds__(256) void prep_hist_kernel(const int* __restrict__ ei,
                                                        int* __restrict__ deg,
                                                        int* __restrict__ rank,
                                                        const float* __restrict__ x,
                                                        ushort* __restrict__ xb,
                                                        const float* __restrict__ W0,
                                                        const float* __restrict__ W1,
                                                        const float* __restrict__ W2,
                                                        const float* __restrict__ W3,
                                                        ushort* __restrict__ Wp,
                                                        float* __restrict__ pooled) {
    uint b = blockIdx.x;
    if (b < HIST_BLOCKS) {
        int e4 = b * 256 + threadIdx.x;
        if (e4 < NE / 4) {
            int4 dst = ((const int4*)(ei + NE))[e4];
            int4 rk;
            rk.x = atomicAdd(&deg[dst.x], 1);
            rk.y = atomicAdd(&deg[dst.y], 1);
            rk.z = atomicAdd(&deg[dst.z], 1);
            rk.w = atomicAdd(&deg[dst.w], 1);
            ((int4*)rank)[e4] = rk;
        }
    } else if (b < HIST_BLOCKS + CONV_BLOCKS) {
        int i = (b - HIST_BLOCKS) * 256 + threadIdx.x;  // < 1,600,000 exactly
        float4 v = ((const float4*)x)[i];
        ushort4 o;
        o.x = f2bf(v.x);
        o.y = f2bf(v.y);
        o.z = f2bf(v.z);
        o.w = f2bf(v.w);
        ((ushort4*)xb)[i] = o;
    } else if (b < HIST_BLOCKS + CONV_BLOCKS + WPREP_BLOCKS) {
        int wu = (b - HIST_BLOCKS - CONV_BLOCKS) * 4 + (threadIdx.x >> 6);
        if (wu >= 128) return;
        int lane = threadIdx.x & 63;
        int m = wu >> 5;
        int g = wu & 31;
        int tile = g >> 2;
        int chunk = g & 3;
        const float* W = (m == 0) ? W0 : (m == 1) ? W1 : (m == 2) ? W2 : W3;
        int col = tile * 16 + (lane & 15);
        int k0 = chunk * 32 + (lane >> 4) * 8;
        ushort* dst = Wp + ((size_t)wu * 64 + lane) * 8;
#pragma unroll
        for (int j = 0; j < 8; ++j) dst[j] = f2bf(W[col * HID + k0 + j]);
    } else {
        int i = (b - HIST_BLOCKS - CONV_BLOCKS - WPREP_BLOCKS) * 256 + threadIdx.x;  // < 16384
        ((float4*)pooled)[i] = make_float4(0.f, 0.f, 0.f, 0.f);
    }
}

// ---------------------------------------------------------------------------
// Scan: per-block exclusive scan (wave shuffle based) -> cross-block fixup
// ---------------------------------------------------------------------------
__global__ __launch_bounds__(256) void scan1_kernel(const int* __restrict__ deg,
                                                    int* __restrict__ row_start,
                                                    int* __restrict__ bsums, int n) {
    __shared__ int wsum[4];
    int i = blockIdx.x * 256 + threadIdx.x;
    int lane = threadIdx.x & 63;
    int wid = threadIdx.x >> 6;
    int v = (i < n) ? deg[i] : 0;
    int sc = v;
#pragma unroll
    for (int off = 1; off < 64; off <<= 1) {
        int t = __shfl_up(sc, off);
        if (lane >= off) sc += t;
    }
    if (lane == 63) wsum[wid] = sc;
    __syncthreads();
    int wpre = 0;
#pragma unroll
    for (int k = 0; k < 4; ++k) wpre += (k < wid) ? wsum[k] : 0;
    if (i < n) row_start[i] = wpre + sc - v;  // block-exclusive
    if (threadIdx.x == 255) bsums[blockIdx.x] = wpre + sc;
}

// merged scan2+scan3: each block reduces bsums[0..blockIdx) and adds.
__global__ __launch_bounds__(256) void scan23_kernel(int* __restrict__ row_start,
                                                     const int* __restrict__ bsums, int n) {
    __shared__ int sred[4];
    int v = (threadIdx.x < blockIdx.x) ? bsums[threadIdx.x] : 0;
#pragma unroll
    for (int off = 32; off > 0; off >>= 1) v += __shfl_xor(v, off);
    if ((threadIdx.x & 63) == 0) sred[threadIdx.x >> 6] = v;
    __syncthreads();
    int total = sred[0] + sred[1] + sred[2] + sred[3];
    int i = blockIdx.x * 256 + threadIdx.x;
    if (i < n) row_start[i] += total;
}

// atomic-free fill, 4 edges/thread. srclist is ushort (node ids < 50000 fit
// 16 bits): halves the scatter footprint (3.2->1.6 MB) and its write-amplified
// HBM traffic, and halves the aggregates' index-stream bytes.
__global__ __launch_bounds__(256) void fill_kernel(const int* __restrict__ ei,
                                                   const int* __restrict__ row_start,
                                                   const int* __restrict__ rank,
                                                   ushort* __restrict__ srclist) {
    int e4 = blockIdx.x * 256 + threadIdx.x;
    if (e4 >= NE / 4) return;
    int4 src = ((const int4*)ei)[e4];
    int4 dst = ((const int4*)(ei + NE))[e4];
    int4 rk = ((const int4*)rank)[e4];
    int p0 = row_start[dst.x] + rk.x;
    int p1 = row_start[dst.y] + rk.y;
    int p2 = row_start[dst.z] + rk.z;
    int p3 = row_start[dst.w] + rk.w;
    srclist[p0] = (ushort)src.x;
    srclist[p1] = (ushort)src.y;
    srclist[p2] = (ushort)src.z;
    srclist[p3] = (ushort)src.w;
}

// ---------------------------------------------------------------------------
// Mean aggregation (bf16): one wave per node (R9 proven-best structure).
// Lane layout: cl = lane&15 -> 16B column chunk (16 x uint4 = 256B row),
//              sub = lane>>4 -> 4 parallel neighbor slots.
// Main loop: 16 neighbors/iter, 4 rows/lane in flight. Tail: one masked
// full-depth round (clamped indices, fma-masked contributions).
// Cross-sub reduction via shfl_xor(16/32). fp32 accumulate, bf16 out.
// ---------------------------------------------------------------------------
__global__ __launch_bounds__(256) void aggregate_kernel(const ushort* __restrict__ feat,
                                                        const int* __restrict__ row_start,
                                                        const int* __restrict__ deg,
                                                        const ushort* __restrict__ srclist,
                                                        ushort* __restrict__ mean, int n) {
    int node = blockIdx.x * 4 + (threadIdx.x >> 6);
    if (node >= n) return;
    int lane = threadIdx.x & 63;
    int cl = lane & 15;
    int sub = lane >> 4;
    const uint4* fb = (const uint4*)feat;  // row stride = 16 uint4
    int s0 = row_start[node];
    int d = deg[node];

    float a[8];
#pragma unroll
    for (int i = 0; i < 8; ++i) a[i] = 0.f;

    int j = 0;
    for (; j + 16 <= d; j += 16) {
        int i0 = srclist[s0 + j + sub];
        int i1 = srclist[s0 + j + 4 + sub];
        int i2 = srclist[s0 + j + 8 + sub];
        int i3 = srclist[s0 + j + 12 + sub];
        uint4 v0 = fb[(size_t)i0 * 16 + cl];
        uint4 v1 = fb[(size_t)i1 * 16 + cl];
        uint4 v2 = fb[(size_t)i2 * 16 + cl];
        uint4 v3 = fb[(size_t)i3 * 16 + cl];
        a[0] += (bf_lo(v0.x) + bf_lo(v1.x)) + (bf_lo(v2.x) + bf_lo(v3.x));
        a[1] += (bf_hi(v0.x) + bf_hi(v1.x)) + (bf_hi(v2.x) + bf_hi(v3.x));
        a[2] += (bf_lo(v0.y) + bf_lo(v1.y)) + (bf_lo(v2.y) + bf_lo(v3.y));
        a[3] += (bf_hi(v0.y) + bf_hi(v1.y)) + (bf_hi(v2.y) + bf_hi(v3.y));
        a[4] += (bf_lo(v0.z) + bf_lo(v1.z)) + (bf_lo(v2.z) + bf_lo(v3.z));
        a[5] += (bf_hi(v0.z) + bf_hi(v1.z)) + (bf_hi(v2.z) + bf_hi(v3.z));
        a[6] += (bf_lo(v0.w) + bf_lo(v1.w)) + (bf_lo(v2.w) + bf_lo(v3.w));
        a[7] += (bf_hi(v0.w) + bf_hi(v1.w)) + (bf_hi(v2.w) + bf_hi(v3.w));
    }
    if (j < d) {
        int dm1 = d - 1;
        int k0 = j + sub;
        int k1 = j + 4 + sub;
        int k2 = j + 8 + sub;
        int k3 = j + 12 + sub;
        int i0 = srclist[s0 + min(k0, dm1)];
        int i1 = srclist[s0 + min(k1, dm1)];
        int i2 = srclist[s0 + min(k2, dm1)];
        int i3 = srclist[s0 + min(k3, dm1)];
        uint4 v0 = fb[(size_t)i0 * 16 + cl];
        uint4 v1 = fb[(size_t)i1 * 16 + cl];
        uint4 v2 = fb[(size_t)i2 * 16 + cl];
        uint4 v3 = fb[(size_t)i3 * 16 + cl];
        float m0 = (k0 < d) ? 1.f : 0.f;
        float m1 = (k1 < d) ? 1.f : 0.f;
        float m2 = (k2 < d) ? 1.f : 0.f;
        float m3 = (k3 < d) ? 1.f : 0.f;
        a[0] += m0 * bf_lo(v0.x) + m1 * bf_lo(v1.x) + m2 * bf_lo(v2.x) + m3 * bf_lo(v3.x);
        a[1] += m0 * bf_hi(v0.x) + m1 * bf_hi(v1.x) + m2 * bf_hi(v2.x) + m3 * bf_hi(v3.x);
        a[2] += m0 * bf_lo(v0.y) + m1 * bf_lo(v1.y) + m2 * bf_lo(v2.y) + m3 * bf_lo(v3.y);
        a[3] += m0 * bf_hi(v0.y) + m1 * bf_hi(v1.y) + m2 * bf_hi(v2.y) + m3 * bf_hi(v3.y);
        a[4] += m0 * bf_lo(v0.z) + m1 * bf_lo(v1.z) + m2 * bf_lo(v2.z) + m3 * bf_lo(v3.z);
        a[5] += m0 * bf_hi(v0.z) + m1 * bf_hi(v1.z) + m2 * bf_hi(v2.z) + m3 * bf_hi(v3.z);
        a[6] += m0 * bf_lo(v0.w) + m1 * bf_lo(v1.w) + m2 * bf_lo(v2.w) + m3 * bf_lo(v3.w);
        a[7] += m0 * bf_hi(v0.w) + m1 * bf_hi(v1.w) + m2 * bf_hi(v2.w) + m3 * bf_hi(v3.w);
    }

#pragma unroll
    for (int i = 0; i < 8; ++i) {
        float v = a[i];
        v += __shfl_xor(v, 16);
        v += __shfl_xor(v, 32);
        a[i] = v;
    }

    if (sub == 0) {
        float inv = 1.0f / fmaxf((float)d, 1.0f);
        uint4 o;
        o.x = (uint)f2bf(a[0] * inv) | ((uint)f2bf(a[1] * inv) << 16);
        o.y = (uint)f2bf(a[2] * inv) | ((uint)f2bf(a[3] * inv) << 16);
        o.z = (uint)f2bf(a[4] * inv) | ((uint)f2bf(a[5] * inv) << 16);
        o.w = (uint)f2bf(a[6] * inv) | ((uint)f2bf(a[7] * inv) << 16);
        ((uint4*)mean)[(size_t)node * 16 + cl] = o;
    }
}

// ---------------------------------------------------------------------------
// MFMA SAGE linear: out = mean @ Wl^T + root @ Wr^T + b.
// One wave per 16 rows x 128 cols; no LDS, no barriers.
// POOL variant fuses global_add_pool: rows grouped by (sorted) batch id,
// fp32 partial sums atomicAdd'ed straight into pooled[g][col].
// ---------------------------------------------------------------------------
template <bool POOL>
__global__ __launch_bounds__(256) void sage_gemm_mfma(const ushort* __restrict__ Amean,
                                                      const ushort* __restrict__ Aroot,
                                                      const ushort* __restrict__ WpL,
                                                      const float* __restrict__ bias,
                                                      const int* __restrict__ batch,
                                                      void* __restrict__ outv, int nwaves) {
    int w = blockIdx.x * 4 + (threadIdx.x >> 6);
    if (w >= nwaves) return;
    int lane = threadIdx.x & 63;
    int mrow = lane & 15;
    int quad = lane >> 4;
    int r0 = w * 16;

    f32x4 acc[8];
#pragma unroll
    for (int t = 0; t < 8; ++t) acc[t] = (f32x4){0.f, 0.f, 0.f, 0.f};

    const ushort* arow_m = Amean + ((size_t)(r0 + mrow)) * HID + quad * 8;
    const ushort* arow_r = Aroot + ((size_t)(r0 + mrow)) * HID + quad * 8;

#pragma unroll
    for (int half = 0; half < 2; ++half) {
        const ushort* arow = half ? arow_r : arow_m;
        const ushort* wb = WpL + (size_t)half * 16384 + (size_t)lane * 8;
#pragma unroll
        for (int c = 0; c < 4; ++c) {
            bf16x8 a = *(const bf16x8*)(arow + c * 32);
#pragma unroll
            for (int t = 0; t < 8; ++t) {
                bf16x8 b = *(const bf16x8*)(wb + (size_t)(t * 4 + c) * 512);
                acc[t] = __builtin_amdgcn_mfma_f32_16x16x32_bf16(a, b, acc[t], 0, 0, 0);
            }
        }
    }

    if (POOL) {
        float* pooled = (float*)outv;
        int rbase = r0 + quad * 4;
        int g0 = batch[rbase + 0];
        int g1 = batch[rbase + 1];
        int g2 = batch[rbase + 2];
        int g3 = batch[rbase + 3];
#pragma unroll
        for (int t = 0; t < 8; ++t) {
            int col = t * 16 + mrow;
            float bv = bias[col];
            float v0 = acc[t][0] + bv;
            float v1 = acc[t][1] + bv;
            float v2 = acc[t][2] + bv;
            float v3 = acc[t][3] + bv;
            int cg = g0;
            float s = v0;
            if (g1 == cg) s += v1; else { atomicAdd(&pooled[(size_t)cg * HID + col], s); cg = g1; s = v1; }
            if (g2 == cg) s += v2; else { atomicAdd(&pooled[(size_t)cg * HID + col], s); cg = g2; s = v2; }
            if (g3 == cg) s += v3; else { atomicAdd(&pooled[(size_t)cg * HID + col], s); cg = g3; s = v3; }
            atomicAdd(&pooled[(size_t)cg * HID + col], s);
        }
    } else {
        ushort* out = (ushort*)outv;
#pragma unroll
        for (int t = 0; t < 8; ++t) {
            int col = t * 16 + mrow;
            float bv = bias[col];
#pragma unroll
            for (int r = 0; r < 4; ++r) {
                int row = r0 + quad * 4 + r;
                out[(size_t)row * HID + col] = f2bf(acc[t][r] + bv);
            }
        }
    }
}

// ---------------------------------------------------------------------------
// Tail: lin1 + BN(eval) + relu + lin2. One block (128 thr) per graph.
// ---------------------------------------------------------------------------
__global__ __launch_bounds__(128) void tail_kernel(const float* __restrict__ pooled,
                                                   const float* __restrict__ lin1_w,
                                                   const float* __restrict__ lin1_b,
                                                   const float* __restrict__ lin2_w,
                                                   const float* __restrict__ lin2_b,
                                                   const float* __restrict__ gamma,
                                                   const float* __restrict__ beta,
                                                   const float* __restrict__ rmean,
                                                   const float* __restrict__ rvar,
                                                   float* __restrict__ out) {
    __shared__ float Wt[64 * 128];  // Wt[k][c ^ (k&31)] = lin1_w[c][k0+k]
    __shared__ float p[128];
    __shared__ float tbuf[128];
    int g = blockIdx.x;
    int c = threadIdx.x;
    p[c] = pooled[g * HID + c];
    float acc = lin1_b[c];
    int kk = c & 63;
    int chalf = c >> 6;
    for (int k0 = 0; k0 < 128; k0 += 64) {
        __syncthreads();
        for (int i = 0; i < 64; ++i) {
            int crow = i * 2 + chalf;
            float v = lin1_w[crow * HID + k0 + kk];
            Wt[kk * 128 + (crow ^ (kk & 31))] = v;
        }
        __syncthreads();
#pragma unroll
        for (int k = 0; k < 64; ++k) {
            acc += p[k0 + k] * Wt[k * 128 + (c ^ (k & 31))];
        }
    }
    float v = (acc - rmean[c]) * rsqrtf(rvar[c] + BN_EPS) * gamma[c] + beta[c];
    v = fmaxf(v, 0.f);
    tbuf[c] = v;
    __syncthreads();
    int j = c >> 6;
    int lane = c & 63;
    float partial = tbuf[lane] * lin2_w[j * HID + lane] +
                    tbuf[lane + 64] * lin2_w[j * HID + lane + 64];
    for (int off = 32; off > 0; off >>= 1) partial += __shfl_down(partial, off);
    if (lane == 0) out[g * 2 + j] = partial + lin2_b[j];
}

// ---------------------------------------------------------------------------
extern "C" void kernel_launch(void* const* d_in, const int* in_sizes, int n_in,
                              void* d_out, int out_size, void* d_ws, size_t ws_size,
                              hipStream_t stream) {
    const float* x = (const float*)d_in[0];
    const int* ei = (const int*)d_in[1];      // [2][E]
    const int* batch = (const int*)d_in[2];   // [N]
    const float* W1l = (const float*)d_in[3];
    const float* b1 = (const float*)d_in[4];
    const float* W1r = (const float*)d_in[5];
    const float* W2l = (const float*)d_in[6];
    const float* b2 = (const float*)d_in[7];
    const float* W2r = (const float*)d_in[8];
    const float* lin1_w = (const float*)d_in[9];
    const float* lin1_b = (const float*)d_in[10];
    const float* lin2_w = (const float*)d_in[11];
    const float* lin2_b = (const float*)d_in[12];
    const float* gamma = (const float*)d_in[13];
    const float* beta = (const float*)d_in[14];
    const float* rmean = (const float*)d_in[15];
    const float* rvar = (const float*)d_in[16];
    float* out = (float*)d_out;

    const int N = NN, E = NE;
    const int NWAVES = N / 16;  // 3125 exact

    // workspace carve (256B aligned)
    char* p = (char*)d_ws;
    auto carve = [&](size_t bytes) {
        void* r = (void*)p;
        p += (bytes + 255) & ~(size_t)255;
        return r;
    };
    int* deg = (int*)carve((size_t)N * 4);
    int* row_start = (int*)carve((size_t)N * 4);
    int* bsums = (int*)carve(1024 * 4);
    int* rank = (int*)carve((size_t)E * 4);
    ushort* srclist = (ushort*)carve((size_t)E * 2 + 64);
    ushort* xb = (ushort*)carve((size_t)N * HID * 2);
    ushort* meanb = (ushort*)carve((size_t)N * HID * 2);
    ushort* h1 = (ushort*)carve((size_t)N * HID * 2);
    float* pooled = (float*)carve((size_t)NG * HID * 4);
    ushort* Wp = (ushort*)carve(4 * 32 * 64 * 8 * 2);  // 128 KB

    // deg must be zero before hist atomics (pooled zeroed inside prep_hist)
    hipMemsetAsync(deg, 0, (size_t)N * 4, stream);

    // merged front-end: hist + convert + weight pack + pooled zero
    prep_hist_kernel<<<PH_GRID, 256, 0, stream>>>(ei, deg, rank, x, xb,
                                                  W1l, W1r, W2l, W2r, Wp, pooled);

    const int scanBlocks = (N + 255) / 256;  // 196
    scan1_kernel<<<scanBlocks, 256, 0, stream>>>(deg, row_start, bsums, N);
    scan23_kernel<<<scanBlocks, 256, 0, stream>>>(row_start, bsums, N);
    fill_kernel<<<(E / 4 + 255) / 256, 256, 0, stream>>>(ei, row_start, rank, srclist);

    // layer 1 (bf16 h1 out)
    aggregate_kernel<<<(N + 3) / 4, 256, 0, stream>>>(xb, row_start, deg, srclist, meanb, N);
    sage_gemm_mfma<false><<<(NWAVES + 3) / 4, 256, 0, stream>>>(meanb, xb, Wp, b1, nullptr, h1,
                                                                NWAVES);
    // layer 2 (fused global_add_pool)
    aggregate_kernel<<<(N + 3) / 4, 256, 0, stream>>>(h1, row_start, deg, srclist, meanb, N);
    sage_gemm_mfma<true><<<(NWAVES + 3) / 4, 256, 0, stream>>>(meanb, h1, Wp + 32768, b2, batch,
                                                               pooled, NWAVES);
    // tail
    tail_kernel<<<NG, 128, 0, stream>>>(pooled, lin1_w, lin1_b, lin2_w, lin2_b,
                                        gamma, beta, rmean, rvar, out);
}